// Round 19
// baseline (238.600 us; speedup 1.0000x reference)
//
#include <hip/hip_runtime.h>
#include <math.h>

// Problem constants
constexpr int Bsz  = 8;
constexpr int Ntok = 1920;
constexpr int Cdim = 512;
constexpr int BLK  = 192;
constexpr int Mrows = Bsz * Ntok;      // 15360
constexpr int NBLK  = Mrows / BLK;     // 80
constexpr float SCALE = 0.02209708691207961f;  // 2048^-0.5
constexpr float LOG2E = 1.4426950408889634f;

typedef _Float16 half8 __attribute__((ext_vector_type(8)));
typedef float    f32x4 __attribute__((ext_vector_type(4)));

#define GLOAD_LDS16(gp, lp) __builtin_amdgcn_global_load_lds( \
    (const __attribute__((address_space(1))) void*)(gp),      \
    (__attribute__((address_space(3))) void*)(lp), 16, 0, 0)

// ---- f16 helpers ----
__device__ inline unsigned short f2h(float f) {
    _Float16 h = (_Float16)f;
    return __builtin_bit_cast(unsigned short, h);
}
__device__ inline float h2f(unsigned short u) {
    return (float)__builtin_bit_cast(_Float16, u);
}

// slot swizzle (involution, applied to global source chunk AND ds_read chunk)
template<int BK> __device__ inline int smask(int r) {
    return (BK == 32) ? ((r & 3) ^ ((r >> 2) & 3)) : (r & 7);
}

// counted vmcnt wait (T4): leave N loads in flight
template<int N> __device__ __forceinline__ void vm_wait() {
    if constexpr (N == 0)      asm volatile("s_waitcnt vmcnt(0)" ::: "memory");
    else if constexpr (N == 2) asm volatile("s_waitcnt vmcnt(2)" ::: "memory");
    else if constexpr (N == 4) asm volatile("s_waitcnt vmcnt(4)" ::: "memory");
    else if constexpr (N == 6) asm volatile("s_waitcnt vmcnt(6)" ::: "memory");
    else                       asm volatile("s_waitcnt vmcnt(8)" ::: "memory");
}

// ---------------- fused g prep: f16 convert + per-row inv-norm (one pass) -------
__global__ __launch_bounds__(256) void prep_g(
    const float* __restrict__ g, unsigned short* __restrict__ gh,
    float* __restrict__ invn)
{
    int wid = threadIdx.x >> 6, lane = threadIdx.x & 63;
    int row = blockIdx.x * 4 + wid;
    const float* p = g + (size_t)row * Cdim + lane * 8;
    float4 v0 = *(const float4*)p;
    float4 v1 = *(const float4*)(p + 4);
    float ss = v0.x * v0.x + v0.y * v0.y + v0.z * v0.z + v0.w * v0.w
             + v1.x * v1.x + v1.y * v1.y + v1.z * v1.z + v1.w * v1.w;
    #pragma unroll
    for (int o = 1; o < 64; o <<= 1) ss += __shfl_xor(ss, o);
    if (lane == 0) invn[row] = 1.0f / fmaxf(sqrtf(ss), 1e-12f);
    ushort4 h0, h1;
    h0.x = f2h(v0.x); h0.y = f2h(v0.y); h0.z = f2h(v0.z); h0.w = f2h(v0.w);
    h1.x = f2h(v1.x); h1.y = f2h(v1.y); h1.z = f2h(v1.z); h1.w = f2h(v1.w);
    ushort4* d = (ushort4*)(gh + (size_t)row * Cdim + lane * 8);
    d[0] = h0; d[1] = h1;
}

// ---------------- token mean (two-stage, reads f16 g) ----------------
__global__ void mean_partial(const unsigned short* __restrict__ gh, float* __restrict__ part) {
    int b = blockIdx.x, t = blockIdx.y, c = threadIdx.x;
    const unsigned short* p = gh + ((size_t)b * Ntok + (size_t)t * 48) * Cdim + c;
    float s = 0.f;
    #pragma unroll 4
    for (int n = 0; n < 48; ++n) s += h2f(p[(size_t)n * Cdim]);
    part[((size_t)b * 40 + t) * Cdim + c] = s;
}

__global__ void mean_final(const float* __restrict__ part, float* __restrict__ meang) {
    int b = blockIdx.x, c = threadIdx.x;
    float s = 0.f;
    for (int t = 0; t < 40; ++t) s += part[((size_t)b * 40 + t) * Cdim + c];
    meang[b * Cdim + c] = s * (1.0f / (float)Ntok);
}

// ---------------- f32 -> f16 convert, optional per-token bias ----------------
__global__ void cvt_k(const float* __restrict__ src, const float* __restrict__ bias,
                      unsigned short* __restrict__ dst, int n4) {
    int i = blockIdx.x * 256 + threadIdx.x;
    if (i >= n4) return;
    float4 v = ((const float4*)src)[i];
    if (bias) {
        int b  = i / (Ntok * Cdim / 4);
        int c4 = (i & (Cdim / 4 - 1)) << 2;
        float4 bv = *(const float4*)&bias[b * Cdim + c4];
        v.x += bv.x; v.y += bv.y; v.z += bv.z; v.w += bv.w;
    }
    ushort4 h;
    h.x = f2h(v.x); h.y = f2h(v.y); h.z = f2h(v.z); h.w = f2h(v.w);
    ((ushort4*)dst)[i] = h;
}

// ---------------- batched 64x64-tiled u16 transpose ----------------
__global__ __launch_bounds__(256) void transpose1(
    const unsigned short* __restrict__ in, unsigned short* __restrict__ out,
    int R, int C, long inB, long outB)
{
    int z = blockIdx.z;
    in  += (size_t)z * inB;
    out += (size_t)z * outB;
    __shared__ unsigned short th[64][68];
    int r0 = blockIdx.y * 64, c0 = blockIdx.x * 64;
    int tr = threadIdx.x >> 4, tc = (threadIdx.x & 15) * 4;
    for (int rr = tr; rr < 64; rr += 16) {
        ushort4 h = *(const ushort4*)&in[(size_t)(r0 + rr) * C + c0 + tc];
        th[tc + 0][rr] = h.x; th[tc + 1][rr] = h.y; th[tc + 2][rr] = h.z; th[tc + 3][rr] = h.w;
    }
    __syncthreads();
    for (int cc = tr; cc < 64; cc += 16) {
        ushort4 h = *(const ushort4*)&th[cc][tc];
        *(ushort4*)&out[(size_t)(c0 + cc) * R + r0 + tc] = h;
    }
}

// ---------------- f16 MFMA GEMM (NT), depth-2 counted-vmcnt pipeline ------------
// psum != null: fused-exp epilogue, e = exp2(v) (alpha pre-folded with log2e),
// row partial sums (32-col granularity) into psum[(z*pM+row)*pSlots + slot].
// OT != null: ALSO write output transposed as OT[b][col][tok] with
// tok = z*BLK + gm, b = tok/Ntok (block-PV g2T fusion).
template<int FM, int FN, int BK>
__global__ __launch_bounds__(256) void mfma_gemm(
    const unsigned short* __restrict__ A, const unsigned short* __restrict__ B,
    float* __restrict__ Of32, unsigned short* __restrict__ Oh,
    int N, int K, int ld,
    long aB, long bB, long oB,
    float alpha, const float* __restrict__ rs, const float* __restrict__ cs, int sB,
    float* __restrict__ psum, int pM, int pSlots,
    unsigned short* __restrict__ OT)
{
    constexpr int BM = FM * 32, BN = FN * 32;
    constexpr int RPC = 512 / BK;
    constexpr int LPR = BK / 8;
    constexpr int NCH = (BM + BN) / RPC;
    constexpr int CPW = NCH / 4;
    int z = blockIdx.z;

    int gx = gridDim.x;
    int nwg = gx * gridDim.y;
    int orig = blockIdx.y * gx + blockIdx.x;
    int q = nwg >> 3, r = nwg & 7;
    int xcd = orig & 7, idx = orig >> 3;
    int wgid = (xcd < r ? xcd * (q + 1) : r * (q + 1) + (xcd - r) * q) + idx;
    int bx = wgid % gx;
    int m0 = (wgid / gx) * BM, n0 = bx * BN;

    __shared__ __align__(16) unsigned short As[2][BM * BK];
    __shared__ __align__(16) unsigned short Bs[2][BN * BK];

    int tid  = threadIdx.x;
    int lane = tid & 63, wid = tid >> 6;
    int wm = (wid >> 1) * (FM * 16), wn = (wid & 1) * (FN * 16);

    int srow = lane / LPR;
    int sgc  = (lane % LPR) ^ smask<BK>(srow);

    const unsigned short* csrc[CPW];
    unsigned short* cdst0[CPW];
    unsigned short* cdst1[CPW];
    #pragma unroll
    for (int i = 0; i < CPW; ++i) {
        int c = wid * CPW + i;
        if (c < BM / RPC) {
            csrc[i]  = A + (size_t)z * aB + (size_t)(m0 + c * RPC + srow) * ld + sgc * 8;
            cdst0[i] = &As[0][c * 512];
            cdst1[i] = &As[1][c * 512];
        } else {
            int cb = c - BM / RPC;
            csrc[i]  = B + (size_t)z * bB + (size_t)(n0 + cb * RPC + srow) * ld + sgc * 8;
            cdst0[i] = &Bs[0][cb * 512];
            cdst1[i] = &Bs[1][cb * 512];
        }
    }

    f32x4 acc[FM][FN] = {};
    int fr = lane & 15, kq = lane >> 4;

    const int nt = K / BK;
    #pragma unroll
    for (int i = 0; i < CPW; ++i) GLOAD_LDS16(csrc[i], cdst0[i]);
    #pragma unroll
    for (int i = 0; i < CPW; ++i) GLOAD_LDS16(csrc[i] + BK, cdst1[i]);

    for (int t = 0; t < nt; ++t) {
        int cur = t & 1;
        if (t + 1 < nt) vm_wait<CPW>(); else vm_wait<0>();
        __builtin_amdgcn_sched_barrier(0);
        __builtin_amdgcn_s_barrier();
        __builtin_amdgcn_sched_barrier(0);

        const unsigned short* Ab = As[cur];
        const unsigned short* Bb = Bs[cur];
        #pragma unroll
        for (int ks = 0; ks < BK / 32; ++ks) {
            int slot = ks * 4 + kq;
            half8 a[FM], b[FN];
            #pragma unroll
            for (int f = 0; f < FM; ++f) {
                int rr = wm + f * 16 + fr;
                a[f] = *(const half8*)&Ab[rr * BK + ((slot ^ smask<BK>(rr)) << 3)];
            }
            #pragma unroll
            for (int f = 0; f < FN; ++f) {
                int rr = wn + f * 16 + fr;
                b[f] = *(const half8*)&Bb[rr * BK + ((slot ^ smask<BK>(rr)) << 3)];
            }
            #pragma unroll
            for (int i = 0; i < FM; ++i)
                #pragma unroll
                for (int j = 0; j < FN; ++j)
                    acc[i][j] = __builtin_amdgcn_mfma_f32_16x16x32_f16(a[i], b[j], acc[i][j], 0, 0, 0);
        }

        __builtin_amdgcn_sched_barrier(0);
        __builtin_amdgcn_s_barrier();
        if (t + 2 < nt) {
            const int k2 = (t + 2) * BK;
            #pragma unroll
            for (int i = 0; i < CPW; ++i)
                GLOAD_LDS16(csrc[i] + k2, cur ? cdst1[i] : cdst0[i]);
        }
    }

    float* O          = Of32 ? Of32 + (size_t)z * oB : nullptr;
    unsigned short* H = Oh   ? Oh   + (size_t)z * oB : nullptr;
    int fq = lane >> 4;
    if (psum) {
        // fused exp2 + row partial sums (alpha already includes log2e)
        int slotB = bx * (BN / 32) + (wn >> 5);
        #pragma unroll
        for (int i = 0; i < FM; ++i) {
            #pragma unroll
            for (int r4 = 0; r4 < 4; ++r4) {
                int gm = m0 + wm + i * 16 + fq * 4 + r4;
                float rf = alpha * (rs ? rs[(size_t)z * sB + gm] : 1.0f);
                float rsum = 0.f;
                #pragma unroll
                for (int j = 0; j < FN; ++j) {
                    int gn = n0 + wn + j * 16 + fr;
                    float v = acc[i][j][r4] * rf * (cs ? cs[(size_t)z * sB + gn] : 1.0f);
                    float e = exp2f(v);
                    H[(size_t)gm * N + gn] = f2h(e);
                    rsum += e;
                }
                rsum += __shfl_xor(rsum, 1);
                rsum += __shfl_xor(rsum, 2);
                rsum += __shfl_xor(rsum, 4);
                rsum += __shfl_xor(rsum, 8);
                if (fr == 0)
                    psum[((size_t)z * pM + gm) * pSlots + slotB] = rsum;
            }
        }
    } else {
        #pragma unroll
        for (int i = 0; i < FM; ++i) {
            #pragma unroll
            for (int r4 = 0; r4 < 4; ++r4) {
                int gm = m0 + wm + i * 16 + fq * 4 + r4;
                float rf = alpha * (rs ? rs[(size_t)z * sB + gm] : 1.0f);
                #pragma unroll
                for (int j = 0; j < FN; ++j) {
                    int gn = n0 + wn + j * 16 + fr;
                    float v = acc[i][j][r4] * rf * (cs ? cs[(size_t)z * sB + gn] : 1.0f);
                    size_t off = (size_t)gm * N + gn;
                    unsigned short hv = f2h(v);
                    if (O) O[off] = v;
                    else   H[off] = hv;
                    if (OT) {
                        int tokg = z * BLK + gm;
                        int b    = tokg / Ntok;
                        int tk   = tokg - b * Ntok;
                        OT[((size_t)b * Cdim + gn) * Ntok + tk] = hv;
                    }
                }
            }
        }
    }
}

// ---------------- 256x256-tile 8-wave f16 GEMM (NT) + fused exp2/row-sums -------
__global__ __launch_bounds__(512, 2) void gemm256(
    const unsigned short* __restrict__ A, const unsigned short* __restrict__ B,
    unsigned short* __restrict__ Oh, float* __restrict__ psum,
    int M, int N, int K, int ld,
    long aB, long bB, long oB, float alpha)   // alpha includes log2e
{
    int z = blockIdx.z;
    int gx = gridDim.x;
    int nwg = gx * gridDim.y;
    int orig = blockIdx.y * gx + blockIdx.x;
    int q = nwg >> 3, r = nwg & 7;
    int xcd = orig & 7, idx = orig >> 3;
    int wgid = (xcd < r ? xcd * (q + 1) : r * (q + 1) + (xcd - r) * q) + idx;
    int bx = wgid % gx;
    int m0 = (wgid / gx) * 256, n0 = bx * 256;

    __shared__ __align__(16) unsigned short As[2][256 * 64];   // 2 x 32 KB
    __shared__ __align__(16) unsigned short Bs[2][256 * 64];   // 2 x 32 KB

    int tid = threadIdx.x, lane = tid & 63, wid = tid >> 6;
    int wr = wid >> 2, wc = wid & 3;       // wave tile: rows wr*128, cols wc*64
    const unsigned short* Az = A + (size_t)z * aB;
    const unsigned short* Bz = B + (size_t)z * bB;

    int srow8 = lane >> 3;
    int sslot = (lane & 7) ^ srow8;

    auto stageT = [&](int t) {
        int cur = t & 1;
        const int koff = t * 64;
        #pragma unroll
        for (int i = 0; i < 4; ++i) {
            int c = wid * 4 + i;               // 0..31
            int rrow = c * 8 + srow8;          // 0..255
            int gr = min(m0 + rrow, M - 1);
            GLOAD_LDS16(Az + (size_t)gr * ld + koff + sslot * 8, &As[cur][c * 512]);
        }
        #pragma unroll
        for (int i = 0; i < 4; ++i) {
            int c = wid * 4 + i;
            int rrow = c * 8 + srow8;
            int gc = min(n0 + rrow, N - 1);
            GLOAD_LDS16(Bz + (size_t)gc * ld + koff + sslot * 8, &Bs[cur][c * 512]);
        }
    };

    f32x4 acc[8][4] = {};
    int fr = lane & 15, kq = lane >> 4;

    const int nt = K / 64;                     // K=512 -> 8
    stageT(0);
    stageT(1);

    for (int t = 0; t < nt; ++t) {
        int cur = t & 1;
        if (t + 1 < nt) vm_wait<8>(); else vm_wait<0>();
        __builtin_amdgcn_sched_barrier(0);
        __builtin_amdgcn_s_barrier();
        __builtin_amdgcn_sched_barrier(0);

        const unsigned short* Ab = As[cur];
        const unsigned short* Bb = Bs[cur];
        __builtin_amdgcn_s_setprio(1);
        half8 b[4][2];
        #pragma unroll
        for (int nf = 0; nf < 4; ++nf) {
            int rr = wc * 64 + nf * 16 + fr;
            #pragma unroll
            for (int ks = 0; ks < 2; ++ks) {
                int slot = (ks * 4 + kq) ^ (rr & 7);
                b[nf][ks] = *(const half8*)&Bb[rr * 64 + slot * 8];
            }
        }
        #pragma unroll
        for (int mf = 0; mf < 8; ++mf) {
            int rr = wr * 128 + mf * 16 + fr;
            half8 a[2];
            #pragma unroll
            for (int ks = 0; ks < 2; ++ks) {
                int slot = (ks * 4 + kq) ^ (rr & 7);
                a[ks] = *(const half8*)&Ab[rr * 64 + slot * 8];
            }
            #pragma unroll
            for (int nf = 0; nf < 4; ++nf)
                #pragma unroll
                for (int ks = 0; ks < 2; ++ks)
                    acc[mf][nf] = __builtin_amdgcn_mfma_f32_16x16x32_f16(
                        a[ks], b[nf][ks], acc[mf][nf], 0, 0, 0);
        }
        __builtin_amdgcn_s_setprio(0);

        __builtin_amdgcn_sched_barrier(0);
        __builtin_amdgcn_s_barrier();
        __builtin_amdgcn_sched_barrier(0);
        if (t + 2 < nt) stageT(t + 2);
    }

    unsigned short* H = Oh + (size_t)z * oB;
    int fq = lane >> 4;
    #pragma unroll
    for (int mi = 0; mi < 8; ++mi) {
        #pragma unroll
        for (int r4 = 0; r4 < 4; ++r4) {
            int gm = m0 + wr * 128 + mi * 16 + fq * 4 + r4;
            bool vrow = gm < M;
            float rsum = 0.f;
            #pragma unroll
            for (int ni = 0; ni < 4; ++ni) {
                int gn = n0 + wc * 64 + ni * 16 + fr;
                float e = exp2f(acc[mi][ni][r4] * alpha);
                if (vrow && gn < N) {
                    H[(size_t)gm * N + gn] = f2h(e);
                    rsum += e;
                }
            }
            rsum += __shfl_xor(rsum, 1);
            rsum += __shfl_xor(rsum, 2);
            rsum += __shfl_xor(rsum, 4);
            rsum += __shfl_xor(rsum, 8);
            if (vrow && fr == 0)
                psum[((size_t)z * M + gm) * 32 + bx * 4 + wc] = rsum;
        }
    }
}

// ---------------- row-sum finalize: inv[row] = 1 / sum(psum[row][0..slots)) -----
__global__ void rowsum_inv(const float* __restrict__ ps, float* __restrict__ inv,
                           int rows, int slots) {
    int i = blockIdx.x * 256 + threadIdx.x;
    if (i >= rows) return;
    const float* p = ps + (size_t)i * slots;
    float s = 0.f;
    for (int j = 0; j < slots; ++j) s += p[j];
    inv[i] = 1.0f / s;
}

// ---------------- launch ----------------
extern "C" void kernel_launch(void* const* d_in, const int* in_sizes, int n_in,
                              void* d_out, int out_size, void* d_ws, size_t ws_size,
                              hipStream_t stream) {
    (void)in_sizes; (void)n_in; (void)out_size; (void)ws_size;
    const float* x  = (const float*)d_in[0];
    const float* g  = (const float*)d_in[1];
    const float* Wq = (const float*)d_in[2];
    const float* Wg = (const float*)d_in[3];
    float* out = (float*)d_out;

    const size_t GE = (size_t)Mrows * Cdim;      // 7,864,320 elems
    const size_t WE = (size_t)Cdim * Cdim;       // 262,144
    char* ws = (char*)d_ws;
    size_t off = 0;
    auto alloc = [&](size_t bytes) { char* p = ws + off; off += (bytes + 255) & ~(size_t)255; return p; };

    float* meang = (float*)alloc(Bsz * Cdim * 4);
    float* part  = (float*)alloc(Bsz * 40 * Cdim * 4);
    float* invn  = (float*)alloc(Mrows * 4);
    unsigned short* gh   = (unsigned short*)alloc(GE * 2);            // g f16
    unsigned short* gTh  = (unsigned short*)alloc(GE * 2);            // [NBLK][512][192]
    unsigned short* qh   = (unsigned short*)alloc(GE * 2);            // q f16; reused as g2T
    unsigned short* wqh  = (unsigned short*)alloc(WE * 2);
    unsigned short* wgh  = (unsigned short*)alloc(WE * 2);
    unsigned short* wqT  = (unsigned short*)alloc(WE * 2);
    unsigned short* wgT  = (unsigned short*)alloc(WE * 2);
    unsigned short* wh   = (unsigned short*)alloc(WE * 2);            // W' = Wg^T·Wq
    unsigned short* qWh  = (unsigned short*)alloc(GE * 2);            // q·W  [15360,512]
    unsigned short* g2h  = (unsigned short*)alloc(GE * 2);
    unsigned short* sbh  = (unsigned short*)alloc((size_t)NBLK * BLK * BLK * 2);
    unsigned short* s2h  = (unsigned short*)alloc((size_t)Bsz * Ntok * Ntok * 2);  // 59 MB
    float* psum   = (float*)alloc((size_t)Mrows * 32 * 4);            // global rowsums
    float* psumb  = (float*)alloc((size_t)Mrows * 6 * 4);             // block rowsums
    float* rsinv  = (float*)alloc((size_t)Mrows * 4);
    float* rsinvb = (float*)alloc((size_t)Mrows * 4);
    unsigned short* g2Th = qh;                                        // [Bsz][512][1920]

    // 1. fused: g -> f16 + per-row inv norms
    prep_g<<<Mrows / 4, 256, 0, stream>>>(g, gh, invn);

    // 1b. token mean from f16 g
    mean_partial<<<dim3(Bsz, 40), 512, 0, stream>>>(gh, part);
    mean_final<<<Bsz, 512, 0, stream>>>(part, meang);

    // 2. conversions + weight transposes
    cvt_k<<<(int)(GE / 4 + 255) / 256, 256, 0, stream>>>(x, meang, qh, (int)(GE / 4));
    cvt_k<<<(int)(WE / 4) / 256, 256, 0, stream>>>(Wq, nullptr, wqh, (int)(WE / 4));
    cvt_k<<<(int)(WE / 4) / 256, 256, 0, stream>>>(Wg, nullptr, wgh, (int)(WE / 4));
    transpose1<<<dim3(8, 8, 1), 256, 0, stream>>>(wqh, wqT, Cdim, Cdim, 0, 0);
    transpose1<<<dim3(8, 8, 1), 256, 0, stream>>>(wgh, wgT, Cdim, Cdim, 0, 0);

    // 2b. W'[c'][c] = sum_d Wg[d,c']*Wq[d,c]
    mfma_gemm<2, 2, 64><<<dim3(8, 8), 256, 0, stream>>>(
        wgT, wqT, nullptr, wh, Cdim, Cdim, Cdim, 0, 0, 0,
        1.0f, nullptr, nullptr, 0, nullptr, 0, 0, nullptr);

    // 2c. gT: per 192-block transpose  [NBLK][512][192]
    transpose1<<<dim3(Cdim / 64, BLK / 64, NBLK), 256, 0, stream>>>(
        gh, gTh, BLK, Cdim, (long)BLK * Cdim, (long)Cdim * BLK);

    // 3. qW = q @ W'^T -> f16  [15360,512]  (<4,4> 128^2 tiles, 480 blocks)
    mfma_gemm<4, 4, 64><<<dim3(Cdim / 128, Mrows / 128), 256, 0, stream>>>(
        qh, wh, nullptr, qWh, Cdim, Cdim, Cdim, 0, 0, 0,
        1.0f, nullptr, nullptr, 0, nullptr, 0, 0, nullptr);

    // 4. block scores -> fused exp2 + rowsums  [80][192][192]
    mfma_gemm<2, 2, 32><<<dim3(3, 3, NBLK), 256, 0, stream>>>(
        gh, gh, nullptr, sbh, BLK, Cdim, Cdim,
        (long)BLK * Cdim, (long)BLK * Cdim, (long)BLK * BLK,
        SCALE * LOG2E, invn, invn, BLK, psumb, BLK, 6, nullptr);

    // 5. block rowsums -> 1/sum
    rowsum_inv<<<(Mrows + 255) / 256, 256, 0, stream>>>(psumb, rsinvb, Mrows, 6);

    // 6. g2 = (e^s · gT^T) * (1/rowsum) -> f16 g2h + transposed g2T (fused)
    mfma_gemm<2, 4, 64><<<dim3(Cdim / 128, BLK / 64, NBLK), 256, 0, stream>>>(
        sbh, gTh, nullptr, g2h, Cdim, BLK, BLK,
        (long)BLK * BLK, (long)Cdim * BLK, (long)BLK * Cdim,
        1.0f, rsinvb, nullptr, BLK, nullptr, 0, 0, g2Th);

    // 7. global scores = qW @ g2^T * SCALE -> e^s (f16) + rowsums  [8][1920][1920]
    gemm256<<<dim3(8, 8, Bsz), 512, 0, stream>>>(
        qWh, g2h, s2h, psum, Ntok, Ntok, Cdim, Cdim,
        (long)Ntok * Cdim, (long)Ntok * Cdim, (long)Ntok * Ntok, SCALE * LOG2E);

    // 8. global rowsums -> 1/sum
    rowsum_inv<<<(Mrows + 255) / 256, 256, 0, stream>>>(psum, rsinv, Mrows, 32);

    // 9. out = (e^s · g2) * (1/rowsum) -> f32  [8][1920][512]
    mfma_gemm<4, 4, 64><<<dim3(Cdim / 128, Ntok / 128, Bsz), 256, 0, stream>>>(
        s2h, g2Th, out, nullptr, Cdim, Ntok, Ntok,
        (long)Ntok * Ntok, (long)Cdim * Ntok, (long)Ntok * Cdim,
        1.0f, rsinv, nullptr, Ntok, nullptr, 0, 0, nullptr);
}

// Round 20
// 220.245 us; speedup vs baseline: 1.0833x; 1.0833x over previous
//
#include <hip/hip_runtime.h>
#include <math.h>

// Problem constants
constexpr int Bsz  = 8;
constexpr int Ntok = 1920;
constexpr int Cdim = 512;
constexpr int BLK  = 192;
constexpr int Mrows = Bsz * Ntok;      // 15360
constexpr int NBLK  = Mrows / BLK;     // 80
constexpr float SCALE = 0.02209708691207961f;  // 2048^-0.5

typedef _Float16 half8 __attribute__((ext_vector_type(8)));
typedef float    f32x4 __attribute__((ext_vector_type(4)));

#define GLOAD_LDS16(gp, lp) __builtin_amdgcn_global_load_lds( \
    (const __attribute__((address_space(1))) void*)(gp),      \
    (__attribute__((address_space(3))) void*)(lp), 16, 0, 0)

// ---- f16 helpers ----
__device__ inline unsigned short f2h(float f) {
    _Float16 h = (_Float16)f;
    return __builtin_bit_cast(unsigned short, h);
}
__device__ inline float h2f(unsigned short u) {
    return (float)__builtin_bit_cast(_Float16, u);
}

// slot swizzle (involution, applied to global source chunk AND ds_read chunk)
template<int BK> __device__ inline int smask(int r) {
    return (BK == 32) ? ((r & 3) ^ ((r >> 2) & 3)) : (r & 7);
}

// counted vmcnt wait (T4): leave N loads in flight
template<int N> __device__ __forceinline__ void vm_wait() {
    if constexpr (N == 0)      asm volatile("s_waitcnt vmcnt(0)" ::: "memory");
    else if constexpr (N == 2) asm volatile("s_waitcnt vmcnt(2)" ::: "memory");
    else if constexpr (N == 4) asm volatile("s_waitcnt vmcnt(4)" ::: "memory");
    else if constexpr (N == 6) asm volatile("s_waitcnt vmcnt(6)" ::: "memory");
    else                       asm volatile("s_waitcnt vmcnt(8)" ::: "memory");
}

// ---------------- fused g prep: f16 convert + per-row inv-norm (one pass) -------
__global__ __launch_bounds__(256) void prep_g(
    const float* __restrict__ g, unsigned short* __restrict__ gh,
    float* __restrict__ invn)
{
    int wid = threadIdx.x >> 6, lane = threadIdx.x & 63;
    int row = blockIdx.x * 4 + wid;
    const float* p = g + (size_t)row * Cdim + lane * 8;
    float4 v0 = *(const float4*)p;
    float4 v1 = *(const float4*)(p + 4);
    float ss = v0.x * v0.x + v0.y * v0.y + v0.z * v0.z + v0.w * v0.w
             + v1.x * v1.x + v1.y * v1.y + v1.z * v1.z + v1.w * v1.w;
    #pragma unroll
    for (int o = 1; o < 64; o <<= 1) ss += __shfl_xor(ss, o);
    if (lane == 0) invn[row] = 1.0f / fmaxf(sqrtf(ss), 1e-12f);
    ushort4 h0, h1;
    h0.x = f2h(v0.x); h0.y = f2h(v0.y); h0.z = f2h(v0.z); h0.w = f2h(v0.w);
    h1.x = f2h(v1.x); h1.y = f2h(v1.y); h1.z = f2h(v1.z); h1.w = f2h(v1.w);
    ushort4* d = (ushort4*)(gh + (size_t)row * Cdim + lane * 8);
    d[0] = h0; d[1] = h1;
}

// ---------------- token mean (two-stage, reads f16 g) ----------------
__global__ void mean_partial(const unsigned short* __restrict__ gh, float* __restrict__ part) {
    int b = blockIdx.x, t = blockIdx.y, c = threadIdx.x;
    const unsigned short* p = gh + ((size_t)b * Ntok + (size_t)t * 48) * Cdim + c;
    float s = 0.f;
    #pragma unroll 4
    for (int n = 0; n < 48; ++n) s += h2f(p[(size_t)n * Cdim]);
    part[((size_t)b * 40 + t) * Cdim + c] = s;
}

__global__ void mean_final(const float* __restrict__ part, float* __restrict__ meang) {
    int b = blockIdx.x, c = threadIdx.x;
    float s = 0.f;
    for (int t = 0; t < 40; ++t) s += part[((size_t)b * 40 + t) * Cdim + c];
    meang[b * Cdim + c] = s * (1.0f / (float)Ntok);
}

// ---------------- f32 -> f16 convert, optional per-token bias ----------------
__global__ void cvt_k(const float* __restrict__ src, const float* __restrict__ bias,
                      unsigned short* __restrict__ dst, int n4) {
    int i = blockIdx.x * 256 + threadIdx.x;
    if (i >= n4) return;
    float4 v = ((const float4*)src)[i];
    if (bias) {
        int b  = i / (Ntok * Cdim / 4);
        int c4 = (i & (Cdim / 4 - 1)) << 2;
        float4 bv = *(const float4*)&bias[b * Cdim + c4];
        v.x += bv.x; v.y += bv.y; v.z += bv.z; v.w += bv.w;
    }
    ushort4 h;
    h.x = f2h(v.x); h.y = f2h(v.y); h.z = f2h(v.z); h.w = f2h(v.w);
    ((ushort4*)dst)[i] = h;
}

// ---------------- batched 64x64-tiled u16 transpose ----------------
__global__ __launch_bounds__(256) void transpose1(
    const unsigned short* __restrict__ in, unsigned short* __restrict__ out,
    int R, int C, long inB, long outB)
{
    int z = blockIdx.z;
    in  += (size_t)z * inB;
    out += (size_t)z * outB;
    __shared__ unsigned short th[64][68];
    int r0 = blockIdx.y * 64, c0 = blockIdx.x * 64;
    int tr = threadIdx.x >> 4, tc = (threadIdx.x & 15) * 4;
    for (int rr = tr; rr < 64; rr += 16) {
        ushort4 h = *(const ushort4*)&in[(size_t)(r0 + rr) * C + c0 + tc];
        th[tc + 0][rr] = h.x; th[tc + 1][rr] = h.y; th[tc + 2][rr] = h.z; th[tc + 3][rr] = h.w;
    }
    __syncthreads();
    for (int cc = tr; cc < 64; cc += 16) {
        ushort4 h = *(const ushort4*)&th[cc][tc];
        *(ushort4*)&out[(size_t)(c0 + cc) * R + r0 + tc] = h;
    }
}

// ---------------- f16 MFMA GEMM (NT), depth-2 counted-vmcnt pipeline ------------
// psum != null: fused-exp epilogue: e = __expf(v), f16 e -> Oh, row partial sums
// (32-col granularity) into psum[(z*pM+row)*pSlots + slot].
template<int FM, int FN, int BK>
__global__ __launch_bounds__(256) void mfma_gemm(
    const unsigned short* __restrict__ A, const unsigned short* __restrict__ B,
    float* __restrict__ Of32, unsigned short* __restrict__ Oh,
    int N, int K, int ld,
    long aB, long bB, long oB,
    float alpha, const float* __restrict__ rs, const float* __restrict__ cs, int sB,
    float* __restrict__ psum, int pM, int pSlots)
{
    constexpr int BM = FM * 32, BN = FN * 32;
    constexpr int RPC = 512 / BK;
    constexpr int LPR = BK / 8;
    constexpr int NCH = (BM + BN) / RPC;
    constexpr int CPW = NCH / 4;
    int z = blockIdx.z;

    int gx = gridDim.x;
    int nwg = gx * gridDim.y;
    int orig = blockIdx.y * gx + blockIdx.x;
    int q = nwg >> 3, r = nwg & 7;
    int xcd = orig & 7, idx = orig >> 3;
    int wgid = (xcd < r ? xcd * (q + 1) : r * (q + 1) + (xcd - r) * q) + idx;
    int bx = wgid % gx;
    int m0 = (wgid / gx) * BM, n0 = bx * BN;

    __shared__ __align__(16) unsigned short As[2][BM * BK];
    __shared__ __align__(16) unsigned short Bs[2][BN * BK];

    int tid  = threadIdx.x;
    int lane = tid & 63, wid = tid >> 6;
    int wm = (wid >> 1) * (FM * 16), wn = (wid & 1) * (FN * 16);

    int srow = lane / LPR;
    int sgc  = (lane % LPR) ^ smask<BK>(srow);

    const unsigned short* csrc[CPW];
    unsigned short* cdst0[CPW];
    unsigned short* cdst1[CPW];
    #pragma unroll
    for (int i = 0; i < CPW; ++i) {
        int c = wid * CPW + i;
        if (c < BM / RPC) {
            csrc[i]  = A + (size_t)z * aB + (size_t)(m0 + c * RPC + srow) * ld + sgc * 8;
            cdst0[i] = &As[0][c * 512];
            cdst1[i] = &As[1][c * 512];
        } else {
            int cb = c - BM / RPC;
            csrc[i]  = B + (size_t)z * bB + (size_t)(n0 + cb * RPC + srow) * ld + sgc * 8;
            cdst0[i] = &Bs[0][cb * 512];
            cdst1[i] = &Bs[1][cb * 512];
        }
    }

    f32x4 acc[FM][FN] = {};
    int fr = lane & 15, kq = lane >> 4;

    const int nt = K / BK;
    #pragma unroll
    for (int i = 0; i < CPW; ++i) GLOAD_LDS16(csrc[i], cdst0[i]);
    #pragma unroll
    for (int i = 0; i < CPW; ++i) GLOAD_LDS16(csrc[i] + BK, cdst1[i]);

    for (int t = 0; t < nt; ++t) {
        int cur = t & 1;
        if (t + 1 < nt) vm_wait<CPW>(); else vm_wait<0>();
        __builtin_amdgcn_sched_barrier(0);
        __builtin_amdgcn_s_barrier();
        __builtin_amdgcn_sched_barrier(0);

        const unsigned short* Ab = As[cur];
        const unsigned short* Bb = Bs[cur];
        #pragma unroll
        for (int ks = 0; ks < BK / 32; ++ks) {
            int slot = ks * 4 + kq;
            half8 a[FM], b[FN];
            #pragma unroll
            for (int f = 0; f < FM; ++f) {
                int rr = wm + f * 16 + fr;
                a[f] = *(const half8*)&Ab[rr * BK + ((slot ^ smask<BK>(rr)) << 3)];
            }
            #pragma unroll
            for (int f = 0; f < FN; ++f) {
                int rr = wn + f * 16 + fr;
                b[f] = *(const half8*)&Bb[rr * BK + ((slot ^ smask<BK>(rr)) << 3)];
            }
            #pragma unroll
            for (int i = 0; i < FM; ++i)
                #pragma unroll
                for (int j = 0; j < FN; ++j)
                    acc[i][j] = __builtin_amdgcn_mfma_f32_16x16x32_f16(a[i], b[j], acc[i][j], 0, 0, 0);
        }

        __builtin_amdgcn_sched_barrier(0);
        __builtin_amdgcn_s_barrier();
        if (t + 2 < nt) {
            const int k2 = (t + 2) * BK;
            #pragma unroll
            for (int i = 0; i < CPW; ++i)
                GLOAD_LDS16(csrc[i] + k2, cur ? cdst1[i] : cdst0[i]);
        }
    }

    float* O          = Of32 ? Of32 + (size_t)z * oB : nullptr;
    unsigned short* H = Oh   ? Oh   + (size_t)z * oB : nullptr;
    int fq = lane >> 4;
    if (psum) {
        int slotB = bx * (BN / 32) + (wn >> 5);
        #pragma unroll
        for (int i = 0; i < FM; ++i) {
            #pragma unroll
            for (int r4 = 0; r4 < 4; ++r4) {
                int gm = m0 + wm + i * 16 + fq * 4 + r4;
                float rf = alpha * (rs ? rs[(size_t)z * sB + gm] : 1.0f);
                float rsum = 0.f;
                #pragma unroll
                for (int j = 0; j < FN; ++j) {
                    int gn = n0 + wn + j * 16 + fr;
                    float v = acc[i][j][r4] * rf * (cs ? cs[(size_t)z * sB + gn] : 1.0f);
                    float e = __expf(v);
                    H[(size_t)gm * N + gn] = f2h(e);
                    rsum += e;
                }
                rsum += __shfl_xor(rsum, 1);
                rsum += __shfl_xor(rsum, 2);
                rsum += __shfl_xor(rsum, 4);
                rsum += __shfl_xor(rsum, 8);
                if (fr == 0)
                    psum[((size_t)z * pM + gm) * pSlots + slotB] = rsum;
            }
        }
    } else {
        #pragma unroll
        for (int i = 0; i < FM; ++i) {
            #pragma unroll
            for (int r4 = 0; r4 < 4; ++r4) {
                int gm = m0 + wm + i * 16 + fq * 4 + r4;
                float rf = alpha * (rs ? rs[(size_t)z * sB + gm] : 1.0f);
                #pragma unroll
                for (int j = 0; j < FN; ++j) {
                    int gn = n0 + wn + j * 16 + fr;
                    float v = acc[i][j][r4] * rf * (cs ? cs[(size_t)z * sB + gn] : 1.0f);
                    size_t off = (size_t)gm * N + gn;
                    if (O) O[off] = v;
                    else   H[off] = f2h(v);
                }
            }
        }
    }
}

// ---------------- 256x256-tile 8-wave f16 GEMM (NT) + fused exp/row-sums --------
__global__ __launch_bounds__(512, 2) void gemm256(
    const unsigned short* __restrict__ A, const unsigned short* __restrict__ B,
    unsigned short* __restrict__ Oh, float* __restrict__ psum,
    int M, int N, int K, int ld,
    long aB, long bB, long oB, float alpha)
{
    int z = blockIdx.z;
    int gx = gridDim.x;
    int nwg = gx * gridDim.y;
    int orig = blockIdx.y * gx + blockIdx.x;
    int q = nwg >> 3, r = nwg & 7;
    int xcd = orig & 7, idx = orig >> 3;
    int wgid = (xcd < r ? xcd * (q + 1) : r * (q + 1) + (xcd - r) * q) + idx;
    int bx = wgid % gx;
    int m0 = (wgid / gx) * 256, n0 = bx * 256;

    __shared__ __align__(16) unsigned short As[2][256 * 64];   // 2 x 32 KB
    __shared__ __align__(16) unsigned short Bs[2][256 * 64];   // 2 x 32 KB

    int tid = threadIdx.x, lane = tid & 63, wid = tid >> 6;
    int wr = wid >> 2, wc = wid & 3;       // wave tile: rows wr*128, cols wc*64
    const unsigned short* Az = A + (size_t)z * aB;
    const unsigned short* Bz = B + (size_t)z * bB;

    int srow8 = lane >> 3;
    int sslot = (lane & 7) ^ srow8;

    auto stageT = [&](int t) {
        int cur = t & 1;
        const int koff = t * 64;
        #pragma unroll
        for (int i = 0; i < 4; ++i) {
            int c = wid * 4 + i;               // 0..31
            int rrow = c * 8 + srow8;          // 0..255
            int gr = min(m0 + rrow, M - 1);
            GLOAD_LDS16(Az + (size_t)gr * ld + koff + sslot * 8, &As[cur][c * 512]);
        }
        #pragma unroll
        for (int i = 0; i < 4; ++i) {
            int c = wid * 4 + i;
            int rrow = c * 8 + srow8;
            int gc = min(n0 + rrow, N - 1);
            GLOAD_LDS16(Bz + (size_t)gc * ld + koff + sslot * 8, &Bs[cur][c * 512]);
        }
    };

    f32x4 acc[8][4] = {};
    int fr = lane & 15, kq = lane >> 4;

    const int nt = K / 64;                     // K=512 -> 8
    stageT(0);
    stageT(1);

    for (int t = 0; t < nt; ++t) {
        int cur = t & 1;
        if (t + 1 < nt) vm_wait<8>(); else vm_wait<0>();
        __builtin_amdgcn_sched_barrier(0);
        __builtin_amdgcn_s_barrier();
        __builtin_amdgcn_sched_barrier(0);

        const unsigned short* Ab = As[cur];
        const unsigned short* Bb = Bs[cur];
        __builtin_amdgcn_s_setprio(1);
        half8 b[4][2];
        #pragma unroll
        for (int nf = 0; nf < 4; ++nf) {
            int rr = wc * 64 + nf * 16 + fr;
            #pragma unroll
            for (int ks = 0; ks < 2; ++ks) {
                int slot = (ks * 4 + kq) ^ (rr & 7);
                b[nf][ks] = *(const half8*)&Bb[rr * 64 + slot * 8];
            }
        }
        #pragma unroll
        for (int mf = 0; mf < 8; ++mf) {
            int rr = wr * 128 + mf * 16 + fr;
            half8 a[2];
            #pragma unroll
            for (int ks = 0; ks < 2; ++ks) {
                int slot = (ks * 4 + kq) ^ (rr & 7);
                a[ks] = *(const half8*)&Ab[rr * 64 + slot * 8];
            }
            #pragma unroll
            for (int nf = 0; nf < 4; ++nf)
                #pragma unroll
                for (int ks = 0; ks < 2; ++ks)
                    acc[mf][nf] = __builtin_amdgcn_mfma_f32_16x16x32_f16(
                        a[ks], b[nf][ks], acc[mf][nf], 0, 0, 0);
        }
        __builtin_amdgcn_s_setprio(0);

        __builtin_amdgcn_sched_barrier(0);
        __builtin_amdgcn_s_barrier();
        __builtin_amdgcn_sched_barrier(0);
        if (t + 2 < nt) stageT(t + 2);
    }

    unsigned short* H = Oh + (size_t)z * oB;
    int fq = lane >> 4;
    #pragma unroll
    for (int mi = 0; mi < 8; ++mi) {
        #pragma unroll
        for (int r4 = 0; r4 < 4; ++r4) {
            int gm = m0 + wr * 128 + mi * 16 + fq * 4 + r4;
            bool vrow = gm < M;
            float rsum = 0.f;
            #pragma unroll
            for (int ni = 0; ni < 4; ++ni) {
                int gn = n0 + wc * 64 + ni * 16 + fr;
                float e = __expf(acc[mi][ni][r4] * alpha);
                if (vrow && gn < N) {
                    H[(size_t)gm * N + gn] = f2h(e);
                    rsum += e;
                }
            }
            rsum += __shfl_xor(rsum, 1);
            rsum += __shfl_xor(rsum, 2);
            rsum += __shfl_xor(rsum, 4);
            rsum += __shfl_xor(rsum, 8);
            if (vrow && fr == 0)
                psum[((size_t)z * M + gm) * 32 + bx * 4 + wc] = rsum;
        }
    }
}

// ---------------- row-sum finalize: inv[row] = 1 / sum(psum[row][0..slots)) -----
__global__ void rowsum_inv(const float* __restrict__ ps, float* __restrict__ inv,
                           int rows, int slots) {
    int i = blockIdx.x * 256 + threadIdx.x;
    if (i >= rows) return;
    const float* p = ps + (size_t)i * slots;
    float s = 0.f;
    for (int j = 0; j < slots; ++j) s += p[j];
    inv[i] = 1.0f / s;
}

// ---------------- launch ----------------
extern "C" void kernel_launch(void* const* d_in, const int* in_sizes, int n_in,
                              void* d_out, int out_size, void* d_ws, size_t ws_size,
                              hipStream_t stream) {
    (void)in_sizes; (void)n_in; (void)out_size; (void)ws_size;
    const float* x  = (const float*)d_in[0];
    const float* g  = (const float*)d_in[1];
    const float* Wq = (const float*)d_in[2];
    const float* Wg = (const float*)d_in[3];
    float* out = (float*)d_out;

    const size_t GE = (size_t)Mrows * Cdim;      // 7,864,320 elems
    const size_t WE = (size_t)Cdim * Cdim;       // 262,144
    char* ws = (char*)d_ws;
    size_t off = 0;
    auto alloc = [&](size_t bytes) { char* p = ws + off; off += (bytes + 255) & ~(size_t)255; return p; };

    float* meang = (float*)alloc(Bsz * Cdim * 4);
    float* part  = (float*)alloc(Bsz * 40 * Cdim * 4);
    float* invn  = (float*)alloc(Mrows * 4);
    unsigned short* gh   = (unsigned short*)alloc(GE * 2);            // g f16
    unsigned short* gTh  = (unsigned short*)alloc(GE * 2);            // [NBLK][512][192]
    unsigned short* qh   = (unsigned short*)alloc(GE * 2);            // q f16; reused as g2T
    unsigned short* wqh  = (unsigned short*)alloc(WE * 2);
    unsigned short* wgh  = (unsigned short*)alloc(WE * 2);
    unsigned short* wqT  = (unsigned short*)alloc(WE * 2);
    unsigned short* wgT  = (unsigned short*)alloc(WE * 2);
    unsigned short* wh   = (unsigned short*)alloc(WE * 2);            // W' = Wg^T·Wq
    unsigned short* qWh  = (unsigned short*)alloc(GE * 2);            // q·W  [15360,512]
    unsigned short* g2h  = (unsigned short*)alloc(GE * 2);
    unsigned short* sbh  = (unsigned short*)alloc((size_t)NBLK * BLK * BLK * 2);
    unsigned short* s2h  = (unsigned short*)alloc((size_t)Bsz * Ntok * Ntok * 2);  // 59 MB
    float* psum   = (float*)alloc((size_t)Mrows * 32 * 4);            // global rowsums
    float* psumb  = (float*)alloc((size_t)Mrows * 6 * 4);             // block rowsums
    float* rsinv  = (float*)alloc((size_t)Mrows * 4);
    float* rsinvb = (float*)alloc((size_t)Mrows * 4);
    unsigned short* g2Th = qh;                                        // [Bsz][512][1920]

    // 1. fused: g -> f16 + per-row inv norms
    prep_g<<<Mrows / 4, 256, 0, stream>>>(g, gh, invn);

    // 1b. token mean from f16 g
    mean_partial<<<dim3(Bsz, 40), 512, 0, stream>>>(gh, part);
    mean_final<<<Bsz, 512, 0, stream>>>(part, meang);

    // 2. conversions + weight transposes
    cvt_k<<<(int)(GE / 4 + 255) / 256, 256, 0, stream>>>(x, meang, qh, (int)(GE / 4));
    cvt_k<<<(int)(WE / 4) / 256, 256, 0, stream>>>(Wq, nullptr, wqh, (int)(WE / 4));
    cvt_k<<<(int)(WE / 4) / 256, 256, 0, stream>>>(Wg, nullptr, wgh, (int)(WE / 4));
    transpose1<<<dim3(8, 8, 1), 256, 0, stream>>>(wqh, wqT, Cdim, Cdim, 0, 0);
    transpose1<<<dim3(8, 8, 1), 256, 0, stream>>>(wgh, wgT, Cdim, Cdim, 0, 0);

    // 2b. W'[c'][c] = sum_d Wg[d,c']*Wq[d,c]
    mfma_gemm<2, 2, 64><<<dim3(8, 8), 256, 0, stream>>>(
        wgT, wqT, nullptr, wh, Cdim, Cdim, Cdim, 0, 0, 0,
        1.0f, nullptr, nullptr, 0, nullptr, 0, 0);

    // 2c. gT: per 192-block transpose  [NBLK][512][192]
    transpose1<<<dim3(Cdim / 64, BLK / 64, NBLK), 256, 0, stream>>>(
        gh, gTh, BLK, Cdim, (long)BLK * Cdim, (long)Cdim * BLK);

    // 3. qW = q @ W'^T -> f16  [15360,512]  (<4,4> 128^2 tiles, 480 blocks)
    mfma_gemm<4, 4, 64><<<dim3(Cdim / 128, Mrows / 128), 256, 0, stream>>>(
        qh, wh, nullptr, qWh, Cdim, Cdim, Cdim, 0, 0, 0,
        1.0f, nullptr, nullptr, 0, nullptr, 0, 0);

    // 4. block scores -> fused exp + rowsums  [80][192][192]
    mfma_gemm<2, 2, 32><<<dim3(3, 3, NBLK), 256, 0, stream>>>(
        gh, gh, nullptr, sbh, BLK, Cdim, Cdim,
        (long)BLK * Cdim, (long)BLK * Cdim, (long)BLK * BLK,
        SCALE, invn, invn, BLK, psumb, BLK, 6);

    // 5. block rowsums -> 1/sum
    rowsum_inv<<<(Mrows + 255) / 256, 256, 0, stream>>>(psumb, rsinvb, Mrows, 6);

    // 6. g2 = (e^s · gT^T) * (1/rowsum) -> f16  [80][192][512]
    mfma_gemm<2, 4, 64><<<dim3(Cdim / 128, BLK / 64, NBLK), 256, 0, stream>>>(
        sbh, gTh, nullptr, g2h, Cdim, BLK, BLK,
        (long)BLK * BLK, (long)Cdim * BLK, (long)BLK * Cdim,
        1.0f, rsinvb, nullptr, BLK, nullptr, 0, 0);

    // 6b. g2T: per-batch transpose  [Bsz][512][1920]  (into dead q buffer)
    transpose1<<<dim3(Cdim / 64, Ntok / 64, Bsz), 256, 0, stream>>>(
        g2h, g2Th, Ntok, Cdim, (long)Ntok * Cdim, (long)Cdim * Ntok);

    // 7. global scores = qW @ g2^T * SCALE -> e^s (f16) + rowsums  [8][1920][1920]
    gemm256<<<dim3(8, 8, Bsz), 512, 0, stream>>>(
        qWh, g2h, s2h, psum, Ntok, Ntok, Cdim, Cdim,
        (long)Ntok * Cdim, (long)Ntok * Cdim, (long)Ntok * Ntok, SCALE);

    // 8. global rowsums -> 1/sum
    rowsum_inv<<<(Mrows + 255) / 256, 256, 0, stream>>>(psum, rsinv, Mrows, 32);

    // 9. out = (e^s · g2) * (1/rowsum) -> f32  [8][1920][512]
    mfma_gemm<4, 4, 64><<<dim3(Cdim / 128, Ntok / 128, Bsz), 256, 0, stream>>>(
        s2h, g2Th, out, nullptr, Cdim, Ntok, Ntok,
        (long)Ntok * Ntok, (long)Cdim * Ntok, (long)Ntok * Cdim,
        1.0f, rsinv, nullptr, Ntok, nullptr, 0, 0);
}

// Round 21
// 214.649 us; speedup vs baseline: 1.1116x; 1.0261x over previous
//
#include <hip/hip_runtime.h>
#include <math.h>

// Problem constants
constexpr int Bsz  = 8;
constexpr int Ntok = 1920;
constexpr int Cdim = 512;
constexpr int BLK  = 192;
constexpr int Mrows = Bsz * Ntok;      // 15360
constexpr int NBLK  = Mrows / BLK;     // 80
constexpr float SCALE = 0.02209708691207961f;  // 2048^-0.5

typedef _Float16 half8 __attribute__((ext_vector_type(8)));
typedef float    f32x4 __attribute__((ext_vector_type(4)));

#define GLOAD_LDS16(gp, lp) __builtin_amdgcn_global_load_lds( \
    (const __attribute__((address_space(1))) void*)(gp),      \
    (__attribute__((address_space(3))) void*)(lp), 16, 0, 0)

// ---- f16 helpers ----
__device__ inline unsigned short f2h(float f) {
    _Float16 h = (_Float16)f;
    return __builtin_bit_cast(unsigned short, h);
}
__device__ inline float h2f(unsigned short u) {
    return (float)__builtin_bit_cast(_Float16, u);
}

// slot swizzle (involution, applied to global source chunk AND ds_read chunk)
template<int BK> __device__ inline int smask(int r) {
    return (BK == 32) ? ((r & 3) ^ ((r >> 2) & 3)) : (r & 7);
}

// counted vmcnt wait (T4): leave N loads in flight
template<int N> __device__ __forceinline__ void vm_wait() {
    if constexpr (N == 0)      asm volatile("s_waitcnt vmcnt(0)" ::: "memory");
    else if constexpr (N == 2) asm volatile("s_waitcnt vmcnt(2)" ::: "memory");
    else if constexpr (N == 4) asm volatile("s_waitcnt vmcnt(4)" ::: "memory");
    else if constexpr (N == 6) asm volatile("s_waitcnt vmcnt(6)" ::: "memory");
    else                       asm volatile("s_waitcnt vmcnt(8)" ::: "memory");
}

// ---------------- fused g prep: f16 convert + per-row inv-norm (one pass) -------
__global__ __launch_bounds__(256) void prep_g(
    const float* __restrict__ g, unsigned short* __restrict__ gh,
    float* __restrict__ invn)
{
    int wid = threadIdx.x >> 6, lane = threadIdx.x & 63;
    int row = blockIdx.x * 4 + wid;
    const float* p = g + (size_t)row * Cdim + lane * 8;
    float4 v0 = *(const float4*)p;
    float4 v1 = *(const float4*)(p + 4);
    float ss = v0.x * v0.x + v0.y * v0.y + v0.z * v0.z + v0.w * v0.w
             + v1.x * v1.x + v1.y * v1.y + v1.z * v1.z + v1.w * v1.w;
    #pragma unroll
    for (int o = 1; o < 64; o <<= 1) ss += __shfl_xor(ss, o);
    if (lane == 0) invn[row] = 1.0f / fmaxf(sqrtf(ss), 1e-12f);
    ushort4 h0, h1;
    h0.x = f2h(v0.x); h0.y = f2h(v0.y); h0.z = f2h(v0.z); h0.w = f2h(v0.w);
    h1.x = f2h(v1.x); h1.y = f2h(v1.y); h1.z = f2h(v1.z); h1.w = f2h(v1.w);
    ushort4* d = (ushort4*)(gh + (size_t)row * Cdim + lane * 8);
    d[0] = h0; d[1] = h1;
}

// ---------------- token mean (two-stage, reads f16 g) ----------------
__global__ void mean_partial(const unsigned short* __restrict__ gh, float* __restrict__ part) {
    int b = blockIdx.x, t = blockIdx.y, c = threadIdx.x;
    const unsigned short* p = gh + ((size_t)b * Ntok + (size_t)t * 48) * Cdim + c;
    float s = 0.f;
    #pragma unroll 4
    for (int n = 0; n < 48; ++n) s += h2f(p[(size_t)n * Cdim]);
    part[((size_t)b * 40 + t) * Cdim + c] = s;
}

__global__ void mean_final(const float* __restrict__ part, float* __restrict__ meang) {
    int b = blockIdx.x, c = threadIdx.x;
    float s = 0.f;
    for (int t = 0; t < 40; ++t) s += part[((size_t)b * 40 + t) * Cdim + c];
    meang[b * Cdim + c] = s * (1.0f / (float)Ntok);
}

// ---------------- f32 -> f16 convert, optional per-token bias ----------------
__global__ void cvt_k(const float* __restrict__ src, const float* __restrict__ bias,
                      unsigned short* __restrict__ dst, int n4) {
    int i = blockIdx.x * 256 + threadIdx.x;
    if (i >= n4) return;
    float4 v = ((const float4*)src)[i];
    if (bias) {
        int b  = i / (Ntok * Cdim / 4);
        int c4 = (i & (Cdim / 4 - 1)) << 2;
        float4 bv = *(const float4*)&bias[b * Cdim + c4];
        v.x += bv.x; v.y += bv.y; v.z += bv.z; v.w += bv.w;
    }
    ushort4 h;
    h.x = f2h(v.x); h.y = f2h(v.y); h.z = f2h(v.z); h.w = f2h(v.w);
    ((ushort4*)dst)[i] = h;
}

// ---------------- fused f32->f16 + transpose (for weights) ----------------
// in: R x C f32 row-major -> out: C x R f16 row-major.
__global__ __launch_bounds__(256) void cvtT(
    const float* __restrict__ in, unsigned short* __restrict__ out, int R, int C)
{
    __shared__ unsigned short th[64][68];
    int r0 = blockIdx.y * 64, c0 = blockIdx.x * 64;
    int tr = threadIdx.x >> 4, tc = (threadIdx.x & 15) * 4;
    for (int rr = tr; rr < 64; rr += 16) {
        float4 v = *(const float4*)&in[(size_t)(r0 + rr) * C + c0 + tc];
        th[tc + 0][rr] = f2h(v.x); th[tc + 1][rr] = f2h(v.y);
        th[tc + 2][rr] = f2h(v.z); th[tc + 3][rr] = f2h(v.w);
    }
    __syncthreads();
    for (int cc = tr; cc < 64; cc += 16) {
        ushort4 h = *(const ushort4*)&th[cc][tc];
        *(ushort4*)&out[(size_t)(c0 + cc) * R + r0 + tc] = h;
    }
}

// ---------------- batched 64x64-tiled u16 transpose ----------------
__global__ __launch_bounds__(256) void transpose1(
    const unsigned short* __restrict__ in, unsigned short* __restrict__ out,
    int R, int C, long inB, long outB)
{
    int z = blockIdx.z;
    in  += (size_t)z * inB;
    out += (size_t)z * outB;
    __shared__ unsigned short th[64][68];
    int r0 = blockIdx.y * 64, c0 = blockIdx.x * 64;
    int tr = threadIdx.x >> 4, tc = (threadIdx.x & 15) * 4;
    for (int rr = tr; rr < 64; rr += 16) {
        ushort4 h = *(const ushort4*)&in[(size_t)(r0 + rr) * C + c0 + tc];
        th[tc + 0][rr] = h.x; th[tc + 1][rr] = h.y; th[tc + 2][rr] = h.z; th[tc + 3][rr] = h.w;
    }
    __syncthreads();
    for (int cc = tr; cc < 64; cc += 16) {
        ushort4 h = *(const ushort4*)&th[cc][tc];
        *(ushort4*)&out[(size_t)(c0 + cc) * R + r0 + tc] = h;
    }
}

// ---------------- f16 MFMA GEMM (NT), depth-2 counted-vmcnt pipeline ------------
// psum != null: fused-exp epilogue: e = __expf(v), f16 e -> Oh, row partial sums
// (32-col granularity) into psum[(z*pM+row)*pSlots + slot].
template<int FM, int FN, int BK>
__global__ __launch_bounds__(256) void mfma_gemm(
    const unsigned short* __restrict__ A, const unsigned short* __restrict__ B,
    float* __restrict__ Of32, unsigned short* __restrict__ Oh,
    int N, int K, int ld,
    long aB, long bB, long oB,
    float alpha, const float* __restrict__ rs, const float* __restrict__ cs, int sB,
    float* __restrict__ psum, int pM, int pSlots)
{
    constexpr int BM = FM * 32, BN = FN * 32;
    constexpr int RPC = 512 / BK;
    constexpr int LPR = BK / 8;
    constexpr int NCH = (BM + BN) / RPC;
    constexpr int CPW = NCH / 4;
    int z = blockIdx.z;

    int gx = gridDim.x;
    int nwg = gx * gridDim.y;
    int orig = blockIdx.y * gx + blockIdx.x;
    int q = nwg >> 3, r = nwg & 7;
    int xcd = orig & 7, idx = orig >> 3;
    int wgid = (xcd < r ? xcd * (q + 1) : r * (q + 1) + (xcd - r) * q) + idx;
    int bx = wgid % gx;
    int m0 = (wgid / gx) * BM, n0 = bx * BN;

    __shared__ __align__(16) unsigned short As[2][BM * BK];
    __shared__ __align__(16) unsigned short Bs[2][BN * BK];

    int tid  = threadIdx.x;
    int lane = tid & 63, wid = tid >> 6;
    int wm = (wid >> 1) * (FM * 16), wn = (wid & 1) * (FN * 16);

    int srow = lane / LPR;
    int sgc  = (lane % LPR) ^ smask<BK>(srow);

    const unsigned short* csrc[CPW];
    unsigned short* cdst0[CPW];
    unsigned short* cdst1[CPW];
    #pragma unroll
    for (int i = 0; i < CPW; ++i) {
        int c = wid * CPW + i;
        if (c < BM / RPC) {
            csrc[i]  = A + (size_t)z * aB + (size_t)(m0 + c * RPC + srow) * ld + sgc * 8;
            cdst0[i] = &As[0][c * 512];
            cdst1[i] = &As[1][c * 512];
        } else {
            int cb = c - BM / RPC;
            csrc[i]  = B + (size_t)z * bB + (size_t)(n0 + cb * RPC + srow) * ld + sgc * 8;
            cdst0[i] = &Bs[0][cb * 512];
            cdst1[i] = &Bs[1][cb * 512];
        }
    }

    f32x4 acc[FM][FN] = {};
    int fr = lane & 15, kq = lane >> 4;

    const int nt = K / BK;
    #pragma unroll
    for (int i = 0; i < CPW; ++i) GLOAD_LDS16(csrc[i], cdst0[i]);
    #pragma unroll
    for (int i = 0; i < CPW; ++i) GLOAD_LDS16(csrc[i] + BK, cdst1[i]);

    for (int t = 0; t < nt; ++t) {
        int cur = t & 1;
        if (t + 1 < nt) vm_wait<CPW>(); else vm_wait<0>();
        __builtin_amdgcn_sched_barrier(0);
        __builtin_amdgcn_s_barrier();
        __builtin_amdgcn_sched_barrier(0);

        const unsigned short* Ab = As[cur];
        const unsigned short* Bb = Bs[cur];
        #pragma unroll
        for (int ks = 0; ks < BK / 32; ++ks) {
            int slot = ks * 4 + kq;
            half8 a[FM], b[FN];
            #pragma unroll
            for (int f = 0; f < FM; ++f) {
                int rr = wm + f * 16 + fr;
                a[f] = *(const half8*)&Ab[rr * BK + ((slot ^ smask<BK>(rr)) << 3)];
            }
            #pragma unroll
            for (int f = 0; f < FN; ++f) {
                int rr = wn + f * 16 + fr;
                b[f] = *(const half8*)&Bb[rr * BK + ((slot ^ smask<BK>(rr)) << 3)];
            }
            #pragma unroll
            for (int i = 0; i < FM; ++i)
                #pragma unroll
                for (int j = 0; j < FN; ++j)
                    acc[i][j] = __builtin_amdgcn_mfma_f32_16x16x32_f16(a[i], b[j], acc[i][j], 0, 0, 0);
        }

        __builtin_amdgcn_sched_barrier(0);
        __builtin_amdgcn_s_barrier();
        if (t + 2 < nt) {
            const int k2 = (t + 2) * BK;
            #pragma unroll
            for (int i = 0; i < CPW; ++i)
                GLOAD_LDS16(csrc[i] + k2, cur ? cdst1[i] : cdst0[i]);
        }
    }

    float* O          = Of32 ? Of32 + (size_t)z * oB : nullptr;
    unsigned short* H = Oh   ? Oh   + (size_t)z * oB : nullptr;
    int fq = lane >> 4;
    if (psum) {
        int slotB = bx * (BN / 32) + (wn >> 5);
        #pragma unroll
        for (int i = 0; i < FM; ++i) {
            #pragma unroll
            for (int r4 = 0; r4 < 4; ++r4) {
                int gm = m0 + wm + i * 16 + fq * 4 + r4;
                float rf = alpha * (rs ? rs[(size_t)z * sB + gm] : 1.0f);
                float rsum = 0.f;
                #pragma unroll
                for (int j = 0; j < FN; ++j) {
                    int gn = n0 + wn + j * 16 + fr;
                    float v = acc[i][j][r4] * rf * (cs ? cs[(size_t)z * sB + gn] : 1.0f);
                    float e = __expf(v);
                    H[(size_t)gm * N + gn] = f2h(e);
                    rsum += e;
                }
                rsum += __shfl_xor(rsum, 1);
                rsum += __shfl_xor(rsum, 2);
                rsum += __shfl_xor(rsum, 4);
                rsum += __shfl_xor(rsum, 8);
                if (fr == 0)
                    psum[((size_t)z * pM + gm) * pSlots + slotB] = rsum;
            }
        }
    } else {
        #pragma unroll
        for (int i = 0; i < FM; ++i) {
            #pragma unroll
            for (int r4 = 0; r4 < 4; ++r4) {
                int gm = m0 + wm + i * 16 + fq * 4 + r4;
                float rf = alpha * (rs ? rs[(size_t)z * sB + gm] : 1.0f);
                #pragma unroll
                for (int j = 0; j < FN; ++j) {
                    int gn = n0 + wn + j * 16 + fr;
                    float v = acc[i][j][r4] * rf * (cs ? cs[(size_t)z * sB + gn] : 1.0f);
                    size_t off = (size_t)gm * N + gn;
                    if (O) O[off] = v;
                    else   H[off] = f2h(v);
                }
            }
        }
    }
}

// ---------------- 256x256-tile 8-wave f16 GEMM (NT) + fused exp/row-sums --------
__global__ __launch_bounds__(512, 2) void gemm256(
    const unsigned short* __restrict__ A, const unsigned short* __restrict__ B,
    unsigned short* __restrict__ Oh, float* __restrict__ psum,
    int M, int N, int K, int ld,
    long aB, long bB, long oB, float alpha)
{
    int z = blockIdx.z;
    int gx = gridDim.x;
    int nwg = gx * gridDim.y;
    int orig = blockIdx.y * gx + blockIdx.x;
    int q = nwg >> 3, r = nwg & 7;
    int xcd = orig & 7, idx = orig >> 3;
    int wgid = (xcd < r ? xcd * (q + 1) : r * (q + 1) + (xcd - r) * q) + idx;
    int bx = wgid % gx;
    int m0 = (wgid / gx) * 256, n0 = bx * 256;

    __shared__ __align__(16) unsigned short As[2][256 * 64];   // 2 x 32 KB
    __shared__ __align__(16) unsigned short Bs[2][256 * 64];   // 2 x 32 KB

    int tid = threadIdx.x, lane = tid & 63, wid = tid >> 6;
    int wr = wid >> 2, wc = wid & 3;       // wave tile: rows wr*128, cols wc*64
    const unsigned short* Az = A + (size_t)z * aB;
    const unsigned short* Bz = B + (size_t)z * bB;

    int srow8 = lane >> 3;
    int sslot = (lane & 7) ^ srow8;

    auto stageT = [&](int t) {
        int cur = t & 1;
        const int koff = t * 64;
        #pragma unroll
        for (int i = 0; i < 4; ++i) {
            int c = wid * 4 + i;               // 0..31
            int rrow = c * 8 + srow8;          // 0..255
            int gr = min(m0 + rrow, M - 1);
            GLOAD_LDS16(Az + (size_t)gr * ld + koff + sslot * 8, &As[cur][c * 512]);
        }
        #pragma unroll
        for (int i = 0; i < 4; ++i) {
            int c = wid * 4 + i;
            int rrow = c * 8 + srow8;
            int gc = min(n0 + rrow, N - 1);
            GLOAD_LDS16(Bz + (size_t)gc * ld + koff + sslot * 8, &Bs[cur][c * 512]);
        }
    };

    f32x4 acc[8][4] = {};
    int fr = lane & 15, kq = lane >> 4;

    const int nt = K / 64;                     // K=512 -> 8
    stageT(0);
    stageT(1);

    for (int t = 0; t < nt; ++t) {
        int cur = t & 1;
        if (t + 1 < nt) vm_wait<8>(); else vm_wait<0>();
        __builtin_amdgcn_sched_barrier(0);
        __builtin_amdgcn_s_barrier();
        __builtin_amdgcn_sched_barrier(0);

        const unsigned short* Ab = As[cur];
        const unsigned short* Bb = Bs[cur];
        __builtin_amdgcn_s_setprio(1);
        half8 b[4][2];
        #pragma unroll
        for (int nf = 0; nf < 4; ++nf) {
            int rr = wc * 64 + nf * 16 + fr;
            #pragma unroll
            for (int ks = 0; ks < 2; ++ks) {
                int slot = (ks * 4 + kq) ^ (rr & 7);
                b[nf][ks] = *(const half8*)&Bb[rr * 64 + slot * 8];
            }
        }
        #pragma unroll
        for (int mf = 0; mf < 8; ++mf) {
            int rr = wr * 128 + mf * 16 + fr;
            half8 a[2];
            #pragma unroll
            for (int ks = 0; ks < 2; ++ks) {
                int slot = (ks * 4 + kq) ^ (rr & 7);
                a[ks] = *(const half8*)&Ab[rr * 64 + slot * 8];
            }
            #pragma unroll
            for (int nf = 0; nf < 4; ++nf)
                #pragma unroll
                for (int ks = 0; ks < 2; ++ks)
                    acc[mf][nf] = __builtin_amdgcn_mfma_f32_16x16x32_f16(
                        a[ks], b[nf][ks], acc[mf][nf], 0, 0, 0);
        }
        __builtin_amdgcn_s_setprio(0);

        __builtin_amdgcn_sched_barrier(0);
        __builtin_amdgcn_s_barrier();
        __builtin_amdgcn_sched_barrier(0);
        if (t + 2 < nt) stageT(t + 2);
    }

    unsigned short* H = Oh + (size_t)z * oB;
    int fq = lane >> 4;
    #pragma unroll
    for (int mi = 0; mi < 8; ++mi) {
        #pragma unroll
        for (int r4 = 0; r4 < 4; ++r4) {
            int gm = m0 + wr * 128 + mi * 16 + fq * 4 + r4;
            bool vrow = gm < M;
            float rsum = 0.f;
            #pragma unroll
            for (int ni = 0; ni < 4; ++ni) {
                int gn = n0 + wc * 64 + ni * 16 + fr;
                float e = __expf(acc[mi][ni][r4] * alpha);
                if (vrow && gn < N) {
                    H[(size_t)gm * N + gn] = f2h(e);
                    rsum += e;
                }
            }
            rsum += __shfl_xor(rsum, 1);
            rsum += __shfl_xor(rsum, 2);
            rsum += __shfl_xor(rsum, 4);
            rsum += __shfl_xor(rsum, 8);
            if (vrow && fr == 0)
                psum[((size_t)z * M + gm) * 32 + bx * 4 + wc] = rsum;
        }
    }
}

// ---------------- row-sum finalize: inv[row] = 1 / sum(psum[row][0..slots)) -----
__global__ void rowsum_inv(const float* __restrict__ ps, float* __restrict__ inv,
                           int rows, int slots) {
    int i = blockIdx.x * 256 + threadIdx.x;
    if (i >= rows) return;
    const float* p = ps + (size_t)i * slots;
    float s = 0.f;
    for (int j = 0; j < slots; ++j) s += p[j];
    inv[i] = 1.0f / s;
}

// ---------------- launch ----------------
extern "C" void kernel_launch(void* const* d_in, const int* in_sizes, int n_in,
                              void* d_out, int out_size, void* d_ws, size_t ws_size,
                              hipStream_t stream) {
    (void)in_sizes; (void)n_in; (void)out_size; (void)ws_size;
    const float* x  = (const float*)d_in[0];
    const float* g  = (const float*)d_in[1];
    const float* Wq = (const float*)d_in[2];
    const float* Wg = (const float*)d_in[3];
    float* out = (float*)d_out;

    const size_t GE = (size_t)Mrows * Cdim;      // 7,864,320 elems
    const size_t WE = (size_t)Cdim * Cdim;       // 262,144
    char* ws = (char*)d_ws;
    size_t off = 0;
    auto alloc = [&](size_t bytes) { char* p = ws + off; off += (bytes + 255) & ~(size_t)255; return p; };

    float* meang = (float*)alloc(Bsz * Cdim * 4);
    float* part  = (float*)alloc(Bsz * 40 * Cdim * 4);
    float* invn  = (float*)alloc(Mrows * 4);
    unsigned short* gh   = (unsigned short*)alloc(GE * 2);            // g f16
    unsigned short* gTh  = (unsigned short*)alloc(GE * 2);            // [NBLK][512][192]
    unsigned short* qh   = (unsigned short*)alloc(GE * 2);            // q f16; reused as g2T
    unsigned short* wqT  = (unsigned short*)alloc(WE * 2);            // Wq^T f16
    unsigned short* wgT  = (unsigned short*)alloc(WE * 2);            // Wg^T f16
    unsigned short* wh   = (unsigned short*)alloc(WE * 2);            // W' = Wg^T·Wq
    unsigned short* qWh  = (unsigned short*)alloc(GE * 2);            // q·W  [15360,512]
    unsigned short* g2h  = (unsigned short*)alloc(GE * 2);
    unsigned short* sbh  = (unsigned short*)alloc((size_t)NBLK * BLK * BLK * 2);
    unsigned short* s2h  = (unsigned short*)alloc((size_t)Bsz * Ntok * Ntok * 2);  // 59 MB
    float* psum   = (float*)alloc((size_t)Mrows * 32 * 4);            // global rowsums
    float* psumb  = (float*)alloc((size_t)Mrows * 6 * 4);             // block rowsums
    float* rsinv  = (float*)alloc((size_t)Mrows * 4);
    float* rsinvb = (float*)alloc((size_t)Mrows * 4);
    unsigned short* g2Th = qh;                                        // [Bsz][512][1920]

    // 1. fused: g -> f16 + per-row inv norms
    prep_g<<<Mrows / 4, 256, 0, stream>>>(g, gh, invn);

    // 1b. token mean from f16 g
    mean_partial<<<dim3(Bsz, 40), 512, 0, stream>>>(gh, part);
    mean_final<<<Bsz, 512, 0, stream>>>(part, meang);

    // 2. conversions; weights: fused f32->f16 + transpose (one pass each)
    cvt_k<<<(int)(GE / 4 + 255) / 256, 256, 0, stream>>>(x, meang, qh, (int)(GE / 4));
    cvtT<<<dim3(8, 8), 256, 0, stream>>>(Wq, wqT, Cdim, Cdim);
    cvtT<<<dim3(8, 8), 256, 0, stream>>>(Wg, wgT, Cdim, Cdim);

    // 2b. W'[c'][c] = sum_d Wg[d,c']*Wq[d,c]
    mfma_gemm<2, 2, 64><<<dim3(8, 8), 256, 0, stream>>>(
        wgT, wqT, nullptr, wh, Cdim, Cdim, Cdim, 0, 0, 0,
        1.0f, nullptr, nullptr, 0, nullptr, 0, 0);

    // 2c. gT: per 192-block transpose  [NBLK][512][192]
    transpose1<<<dim3(Cdim / 64, BLK / 64, NBLK), 256, 0, stream>>>(
        gh, gTh, BLK, Cdim, (long)BLK * Cdim, (long)Cdim * BLK);

    // 3. qW = q @ W'^T -> f16  [15360,512]  (<4,4> 128^2 tiles, 480 blocks)
    mfma_gemm<4, 4, 64><<<dim3(Cdim / 128, Mrows / 128), 256, 0, stream>>>(
        qh, wh, nullptr, qWh, Cdim, Cdim, Cdim, 0, 0, 0,
        1.0f, nullptr, nullptr, 0, nullptr, 0, 0);

    // 4. block scores -> fused exp + rowsums  [80][192][192]  (BK64)
    mfma_gemm<2, 2, 64><<<dim3(3, 3, NBLK), 256, 0, stream>>>(
        gh, gh, nullptr, sbh, BLK, Cdim, Cdim,
        (long)BLK * Cdim, (long)BLK * Cdim, (long)BLK * BLK,
        SCALE, invn, invn, BLK, psumb, BLK, 6);

    // 5. block rowsums -> 1/sum
    rowsum_inv<<<(Mrows + 255) / 256, 256, 0, stream>>>(psumb, rsinvb, Mrows, 6);

    // 6. g2 = (e^s · gT^T) * (1/rowsum) -> f16  [80][192][512]
    mfma_gemm<2, 4, 64><<<dim3(Cdim / 128, BLK / 64, NBLK), 256, 0, stream>>>(
        sbh, gTh, nullptr, g2h, Cdim, BLK, BLK,
        (long)BLK * BLK, (long)Cdim * BLK, (long)BLK * Cdim,
        1.0f, rsinvb, nullptr, BLK, nullptr, 0, 0);

    // 6b. g2T: per-batch transpose  [Bsz][512][1920]  (into dead q buffer)
    transpose1<<<dim3(Cdim / 64, Ntok / 64, Bsz), 256, 0, stream>>>(
        g2h, g2Th, Ntok, Cdim, (long)Ntok * Cdim, (long)Cdim * Ntok);

    // 7. global scores = qW @ g2^T * SCALE -> e^s (f16) + rowsums  [8][1920][1920]
    gemm256<<<dim3(8, 8, Bsz), 512, 0, stream>>>(
        qWh, g2h, s2h, psum, Ntok, Ntok, Cdim, Cdim,
        (long)Ntok * Cdim, (long)Ntok * Cdim, (long)Ntok * Ntok, SCALE);

    // 8. global rowsums -> 1/sum
    rowsum_inv<<<(Mrows + 255) / 256, 256, 0, stream>>>(psum, rsinv, Mrows, 32);

    // 9. out = (e^s · g2) * (1/rowsum) -> f32  [8][1920][512]
    mfma_gemm<4, 4, 64><<<dim3(Cdim / 128, Ntok / 128, Bsz), 256, 0, stream>>>(
        s2h, g2Th, out, nullptr, Cdim, Ntok, Ntok,
        (long)Ntok * Ntok, (long)Cdim * Ntok, (long)Ntok * Cdim,
        1.0f, rsinv, nullptr, Ntok, nullptr, 0, 0);
}